// Round 9
// baseline (1297.698 us; speedup 1.0000x reference)
//
#include <hip/hip_runtime.h>
#include <cmath>

// ConceptLearner LSTM on MI355X.
// Sizes: B=64, S=128, D=64, H=256 (4H=1024 gates), P=1024, V*R=32000.
// R9: k_mega blocks widened 512 -> 1024 threads (16 waves, 4/SIMD), one gate
// tile per wave (was two). Same total work/CU; 2x resident waves to hide the
// per-step dependency chain (ds_read->MFMA->transcendental->ds_write->barrier).
// bres 192->96 VGPR/wave (spill-safe). Chunk depth back to 2 (best measured).

typedef _Float16 f16;
typedef _Float16 f16x8 __attribute__((ext_vector_type(8)));
typedef _Float16 f16x4 __attribute__((ext_vector_type(4)));
typedef float f32x4 __attribute__((ext_vector_type(4)));

#define MFMA(a,b,c) __builtin_amdgcn_mfma_f32_16x16x32_f16((a),(b),(c),0,0,0)
#define LSTR 280   // LDS row stride in f16
#define FPAD 32    // flag padding: 32 ints = 128 B per flag

__device__ __forceinline__ float frcp(float x) { return __builtin_amdgcn_rcpf(x); }
__device__ __forceinline__ float sigf(float x)  { return frcp(1.f + __expf(-x)); }
__device__ __forceinline__ float tanhf_(float x){ return 1.f - 2.f*frcp(__expf(2.f*x) + 1.f); }

// Relaxed spin until flag >= target, then one acquire load (inv) to fence data.
__device__ __forceinline__ void wait_flag(int* f, int target) {
    while (__hip_atomic_load(f, __ATOMIC_RELAXED, __HIP_MEMORY_SCOPE_AGENT) < target)
        __builtin_amdgcn_s_sleep(1);
    (void)__hip_atomic_load(f, __ATOMIC_ACQUIRE, __HIP_MEMORY_SCOPE_AGENT);
}

// ---------------------------------------------------------------- convert ---
__global__ void k_convert(const float* __restrict__ Wih0, const float* __restrict__ Whh0,
                          const float* __restrict__ bih0, const float* __restrict__ bhh0,
                          const float* __restrict__ Wih1, const float* __restrict__ Whh1,
                          const float* __restrict__ bih1, const float* __restrict__ bhh1,
                          f16* __restrict__ w16, float* __restrict__ bsum,
                          int* __restrict__ flg)
{
    int i = blockIdx.x * 256 + threadIdx.x;           // grid 1024*256
    if (i < 65536)  w16[i] = (f16)Wih0[i];            // Wih0 [1024][64]
    if (i < 262144) {
        w16[65536  + i] = (f16)Whh0[i];               // Whh0 [1024][256]
        w16[327680 + i] = (f16)Wih1[i];               // Wih1 [1024][256]
        w16[589824 + i] = (f16)Whh1[i];               // Whh1 [1024][256]
    }
    if (i < 1024) { bsum[i] = bih0[i] + bhh0[i]; bsum[1024 + i] = bih1[i] + bhh1[i]; }
    if (i < 16*FPAD) flg[i] = 0;                      // padded pipeline flags
}

// ------------------------------------------------- input projection (MFMA) --
// out preacts stored f16, gate-interleaved: row offset = ti*64 + col*4 + gate.
// CVT=true: A is fp32 (x1 rows 0..8191, x2 rows 8192..16383), cast inline.
template<int K, bool CVT>
__global__ __launch_bounds__(512)
void k_proj(const void* __restrict__ A0v, const void* __restrict__ A1v,
            const f16* __restrict__ Bw, const float* __restrict__ bias,
            f16* __restrict__ out)
{
    const int w = threadIdx.x >> 6, lane = threadIdx.x & 63;
    const int quad = lane >> 4, l16 = lane & 15;
    const long m0 = (long)blockIdx.x * 128 + w * 16;   // wave's M-tile
    f32x4 acc[2][4] = {};
    #pragma unroll
    for (int kc = 0; kc < K/32; ++kc) {
        const int ko = kc*32 + quad*8;
        f16x8 a;
        if (CVT) {
            const float* Af = (const float*)((m0 < 8192) ? A0v : A1v);
            const float* ap = Af + ((m0 & 8191) + l16)*K + ko;
            float4 v0 = *(const float4*)ap, v1 = *(const float4*)(ap + 4);
            a[0]=(f16)v0.x; a[1]=(f16)v0.y; a[2]=(f16)v0.z; a[3]=(f16)v0.w;
            a[4]=(f16)v1.x; a[5]=(f16)v1.y; a[6]=(f16)v1.z; a[7]=(f16)v1.w;
        } else {
            a = *(const f16x8*)((const f16*)A0v + (m0 + l16)*K + ko);
        }
        #pragma unroll
        for (int tg = 0; tg < 2; ++tg) {
            const int ti = blockIdx.y*2 + tg;
            #pragma unroll
            for (int g = 0; g < 4; ++g) {
                f16x8 b = *(const f16x8*)(Bw + (long)(g*256 + ti*16 + l16)*K + ko);
                acc[tg][g] = MFMA(a, b, acc[tg][g]);
            }
        }
    }
    #pragma unroll
    for (int tg = 0; tg < 2; ++tg) {
        const int ti = blockIdx.y*2 + tg;
        float bi[4];
        #pragma unroll
        for (int g = 0; g < 4; ++g) bi[g] = bias[g*256 + ti*16 + l16];
        #pragma unroll
        for (int r = 0; r < 4; ++r) {                  // D: row=quad*4+r, col=lane&15
            long mm = m0 + quad*4 + r;
            f16x4 pv;
            #pragma unroll
            for (int g = 0; g < 4; ++g) pv[g] = (f16)(acc[tg][g][r] + bi[g]);
            *(f16x4*)(out + mm*1024 + ti*64 + l16*4) = pv;
        }
    }
}

// --------------------------------------------- pipelined LSTM mega-kernel ---
// 24 blocks x 1024 thr (16 waves; wave w owns gate tile ti=w).
// role = blockIdx>>3: 0=layer0, 1=xg1 projection, 2=layer1. g = blockIdx&7.
// 2-step chunks: flags[g*FPAD] h0 progress (released at even s);
//                flags[(8+g)*FPAD] xg1 progress (released at odd s).
__global__ __launch_bounds__(1024, 4)
void k_mega(const f16* __restrict__ w16, const f16* __restrict__ xg0,
            f16* __restrict__ xg1, f16* __restrict__ h0s,
            const float* __restrict__ bsum1, float* __restrict__ out_enc,
            int* __restrict__ flags)
{
    __shared__ f16 wl[256*LSTR];    // o-gate rows 768..1023 of this role's W
    __shared__ f16 hb[2*16*LSTR];   // double-buffered h (lstm roles only)
    const int tid = threadIdx.x;
    const int w = tid >> 6, lane = tid & 63;   // w = gate tile ti (0..15)
    const int quad = lane >> 4, l16 = lane & 15;
    const int role = blockIdx.x >> 3, g = blockIdx.x & 7;
    int* fl_h0  = flags + g*FPAD;
    int* fl_xg1 = flags + (8+g)*FPAD;

    const f16* W = (role == 0) ? w16 + 65536           // Whh0
                 : (role == 1) ? w16 + 327680          // Wih1
                               : w16 + 589824;         // Whh1

    // resident b-frags: slot 0=i (tile w), 1=f (16+w), 2=g (32+w)
    f16x8 bres[3][8];
    #pragma unroll
    for (int s3 = 0; s3 < 3; ++s3) {
        const int tile = s3*16 + w;
        #pragma unroll
        for (int kc = 0; kc < 8; ++kc)
            bres[s3][kc] = *(const f16x8*)(W + (tile*16 + l16)*256 + kc*32 + quad*8);
    }
    {   // stage o-gate rows into LDS (coalesced, once)
        const int r = tid >> 2, hh = tid & 3;
        const f16* src = W + (768 + r)*256 + hh*64;
        f16* dst = wl + r*LSTR + hh*64;
        #pragma unroll
        for (int j = 0; j < 8; ++j)
            *(f16x8*)(dst + j*8) = *(const f16x8*)(src + j*8);
    }

    if (role == 1) {    // ---------------- projection stage: xg1(s) = h0(s)@Wih1^T + b
        float bi[4];
        #pragma unroll
        for (int g4 = 0; g4 < 4; ++g4) bi[g4] = bsum1[g4*256 + w*16 + l16];
        __syncthreads();
        #pragma unroll 1
        for (int s = 0; s < 128; ++s) {
            if ((s & 1) == 0) {              // chunk head: wait for h0(s), h0(s+1)
                if (tid == 0) wait_flag(fl_h0, s + 2);
                __syncthreads();
            }
            const f16* hrow = h0s + ((long)s*128 + g*16 + l16)*256 + quad*8;
            f16x8 av[8];
            #pragma unroll
            for (int kc = 0; kc < 8; ++kc) av[kc] = *(const f16x8*)(hrow + kc*32);
            f32x4 ai = {}, af = {}, ag = {}, ao = {};
            #pragma unroll
            for (int kc = 0; kc < 8; ++kc) {
                f16x8 bo = *(const f16x8*)(wl + (w*16 + l16)*LSTR + kc*32 + quad*8);
                ai = MFMA(av[kc], bres[0][kc], ai);
                af = MFMA(av[kc], bres[1][kc], af);
                ag = MFMA(av[kc], bres[2][kc], ag);
                ao = MFMA(av[kc], bo,          ao);
            }
            #pragma unroll
            for (int r = 0; r < 4; ++r) {
                f16x4 pv;
                pv[0] = (f16)(ai[r] + bi[0]);
                pv[1] = (f16)(af[r] + bi[1]);
                pv[2] = (f16)(ag[r] + bi[2]);
                pv[3] = (f16)(ao[r] + bi[3]);
                *(f16x4*)(xg1 + ((long)(g*16 + quad*4 + r)*128 + s)*1024
                              + w*64 + l16*4) = pv;
            }
            if (s & 1) {                     // chunk tail: drain stores, release
                __syncthreads();             // vmcnt(0) before s_barrier
                if (tid == 0)
                    __hip_atomic_store(fl_xg1, s + 1, __ATOMIC_RELEASE,
                                       __HIP_MEMORY_SCOPE_AGENT);
            }
        }
        return;
    }

    // ---------------- LSTM stages (role 0 = layer0, role 2 = layer1) ----------
    for (int i = tid; i < 2*16*LSTR; i += 1024) hb[i] = (f16)0.f;   // h(-1)=0

    const f16* xg = (role == 0) ? xg0 : xg1;
    const f16* xp[4];
    #pragma unroll
    for (int r = 0; r < 4; ++r)
        xp[r] = xg + (long)(g*16 + quad*4 + r)*131072 + w*64 + l16*4;

    float c[4]    = {0,0,0,0};
    float oacc[4] = {0,0,0,0};
    __syncthreads();

    #pragma unroll 1
    for (int s = 0; s < 128; ++s) {
        const int rb = s & 1, wb = rb ^ 1;
        if (role == 2 && (s & 1) == 0) {     // chunk head: wait for xg1(s), xg1(s+1)
            if (tid == 0) wait_flag(fl_xg1, s + 2);
            __syncthreads();
        }
        if (role == 0 && s > 0) {   // h(s-1) -> global (step-major), off critical path
            const int cc = tid >> 6, kk = (tid & 63) * 4;
            f16x4 hv = *(const f16x4*)(hb + (rb*16 + cc)*LSTR + kk);
            *(f16x4*)(h0s + ((long)(s-1)*128 + g*16 + cc)*256 + kk) = hv;
        }
        f16x4 xv[4];
        #pragma unroll
        for (int r = 0; r < 4; ++r) xv[r] = *(const f16x4*)(xp[r]);
        f32x4 ai = {}, af = {}, ag = {}, ao = {};
        #pragma unroll
        for (int kc = 0; kc < 8; ++kc) {
            f16x8 a  = *(const f16x8*)(hb + (rb*16 + l16)*LSTR + kc*32 + quad*8);
            f16x8 bo = *(const f16x8*)(wl + (w*16 + l16)*LSTR + kc*32 + quad*8);
            ai = MFMA(a, bres[0][kc], ai);
            af = MFMA(a, bres[1][kc], af);
            ag = MFMA(a, bres[2][kc], ag);
            ao = MFMA(a, bo,          ao);
        }
        #pragma unroll
        for (int r = 0; r < 4; ++r) {
            float gi = sigf(ai[r] + (float)xv[r][0]);
            float gf = sigf(af[r] + (float)xv[r][1]);
            float gg = tanhf_(ag[r] + (float)xv[r][2]);
            float go = sigf(ao[r] + (float)xv[r][3]);
            float cn = gf*c[r] + gi*gg;
            c[r] = cn;
            float hn = go * tanhf_(cn);
            if (role == 2) oacc[r] += hn;
            hb[(wb*16 + quad*4 + r)*LSTR + w*16 + l16] = (f16)hn;
        }
        #pragma unroll
        for (int r = 0; r < 4; ++r) xp[r] += 1024;
        __syncthreads();           // drains the h(s-1) global store (vmcnt)
        // release at even steps s>=2: h0(0..s-1) globally visible
        if (role == 0 && (s & 1) == 0 && s > 0 && tid == 0)
            __hip_atomic_store(fl_h0, s, __ATOMIC_RELEASE,
                               __HIP_MEMORY_SCOPE_AGENT);
    }
    if (role == 0) {       // final history entry h(127): buffer rb(128)=0
        const int cc = tid >> 6, kk = (tid & 63) * 4;
        f16x4 hv = *(const f16x4*)(hb + (0*16 + cc)*LSTR + kk);
        *(f16x4*)(h0s + ((long)127*128 + g*16 + cc)*256 + kk) = hv;
        __syncthreads();
        if (tid == 0)
            __hip_atomic_store(fl_h0, 128, __ATOMIC_RELEASE,
                               __HIP_MEMORY_SCOPE_AGENT);
    }
    if (role == 2) {       // time-summed hidden state -> encoder output
        #pragma unroll
        for (int r = 0; r < 4; ++r)
            out_enc[(long)(g*16 + quad*4 + r)*256 + w*16 + l16] = oacc[r];
    }
}

// ----------------------------------------------------- fp32 FC (head) -------
// MODE 0: gelu (A = concat(enc0,enc1)) -> fp32 out; MODE 1: res+relu then
// fused BatchNorm (block owns all 64 rows of its 32 cols) -> f16 out16.
template<int K, int MODE>
__global__ __launch_bounds__(256)
void k_fc(const float* __restrict__ A, const float* __restrict__ W,
          const float* __restrict__ bias, const float* __restrict__ res,
          const float* __restrict__ bng, const float* __restrict__ bnb,
          float* __restrict__ out, f16* __restrict__ out16, const int Nst)
{
    __shared__ float ws[32*64];
    __shared__ float as[64*64];   // [k][m]; MODE 1 reuses as stride-33 stats buffer
    __shared__ float mus[32], rss[32];
    const int tid = threadIdx.x;
    const int n0 = blockIdx.x * 32;
    const int m2 = tid & 31, ndg = tid >> 5;
    float acc[2][4] = {};
    for (int kc = 0; kc < K/64; ++kc) {
        __syncthreads();
        {   // stage W [32 cols][64 k]
            const int col = tid >> 3, k8 = (tid & 7)*8;
            const float* src = W + (long)(n0 + col)*K + kc*64 + k8;
            *(float4*)(ws + col*64 + k8)     = *(const float4*)(src);
            *(float4*)(ws + col*64 + k8 + 4) = *(const float4*)(src + 4);
        }
        {   // stage A transposed: as[k][m]
            const int m = tid >> 2, j4 = (tid & 3)*16;
            #pragma unroll
            for (int i4 = 0; i4 < 4; ++i4) {
                const int kk = kc*64 + j4 + i4*4;
                const float* srcA;
                if (MODE == 0) srcA = (kk < 256) ? (A + (long)m*256 + kk)
                                                 : (A + 16384 + (long)m*256 + kk - 256);
                else           srcA = A + (long)m*K + kk;
                float4 v = *(const float4*)srcA;
                as[(j4 + i4*4 + 0)*64 + m] = v.x;
                as[(j4 + i4*4 + 1)*64 + m] = v.y;
                as[(j4 + i4*4 + 2)*64 + m] = v.z;
                as[(j4 + i4*4 + 3)*64 + m] = v.w;
            }
        }
        __syncthreads();
        #pragma unroll 4
        for (int k4 = 0; k4 < 64; k4 += 4) {
            float a0[4], a1[4];
            #pragma unroll
            for (int i = 0; i < 4; ++i) {
                a0[i] = as[(k4+i)*64 + m2];
                a1[i] = as[(k4+i)*64 + m2 + 32];
            }
            #pragma unroll
            for (int j = 0; j < 4; ++j) {
                const float4 wv = *(const float4*)(ws + (ndg*4 + j)*64 + k4);
                acc[0][j] += a0[0]*wv.x + a0[1]*wv.y + a0[2]*wv.z + a0[3]*wv.w;
                acc[1][j] += a1[0]*wv.x + a1[1]*wv.y + a1[2]*wv.z + a1[3]*wv.w;
            }
        }
    }
    if (MODE == 1) {                       // res + relu, then fused BatchNorm
        float vv[2][4];
        #pragma unroll
        for (int i = 0; i < 2; ++i)
            #pragma unroll
            for (int j = 0; j < 4; ++j) {
                const int m = m2 + i*32, nn = n0 + ndg*4 + j;
                vv[i][j] = res[(long)m*1024 + nn] + fmaxf(acc[i][j] + bias[nn], 0.f);
            }
        __syncthreads();                    // as[] compute reads done
        #pragma unroll
        for (int i = 0; i < 2; ++i)
            #pragma unroll
            for (int j = 0; j < 4; ++j)
                as[(m2 + i*32)*33 + ndg*4 + j] = vv[i][j];   // stride 33: skewed banks
        __syncthreads();
        if (tid < 32) {
            float s = 0.f, ss = 0.f;
            #pragma unroll 4
            for (int m = 0; m < 64; ++m) {
                float x = as[m*33 + tid];
                s += x; ss += x*x;
            }
            const float mu = s * (1.f/64.f);
            mus[tid] = mu;
            rss[tid] = rsqrtf(ss * (1.f/64.f) - mu*mu + 1e-5f);
        }
        __syncthreads();
        #pragma unroll
        for (int i = 0; i < 2; ++i)
            #pragma unroll
            for (int j = 0; j < 4; ++j) {
                const int m = m2 + i*32, cl = ndg*4 + j, nn = n0 + cl;
                out16[(long)m*Nst + nn] =
                    (f16)((vv[i][j] - mus[cl]) * rss[cl] * bng[nn] + bnb[nn]);
            }
        return;
    }
    #pragma unroll
    for (int i = 0; i < 2; ++i) {
        const int m = m2 + i*32;
        #pragma unroll
        for (int j = 0; j < 4; ++j) {
            const int nn = n0 + ndg*4 + j;
            float v = acc[i][j] + bias[nn];
            v = 0.5f * v * (1.0f + erff(v * 0.7071067811865475f));
            out[(long)m*Nst + nn] = v;
        }
    }
}

// ------------------------------------- fc3: MFMA, W converted inline --------
// scores[m][n] = relu(h3f16[m][:] . fc3_w[n][:] + b[n]); M=64, N=32000, K=1024.
// W streamed from HBM as fp32 (used once), cast to f16 in-register; A f16 L2-hot.
__global__ __launch_bounds__(256)
void k_fc3(const f16* __restrict__ A, const float* __restrict__ W,
           const float* __restrict__ bias, float* __restrict__ out)
{
    const int w = threadIdx.x >> 6, lane = threadIdx.x & 63;
    const int quad = lane >> 4, l16 = lane & 15;
    const int m0 = w*16, n0 = blockIdx.x*64;
    f32x4 acc[4] = {};
    #pragma unroll 1
    for (int kc = 0; kc < 32; ++kc) {
        const int ko = kc*32 + quad*8;
        f16x8 a = *(const f16x8*)(A + (m0 + l16)*1024 + ko);
        #pragma unroll
        for (int nt = 0; nt < 4; ++nt) {
            const float* wp = W + (long)(n0 + nt*16 + l16)*1024 + ko;
            float4 v0 = *(const float4*)wp, v1 = *(const float4*)(wp + 4);
            f16x8 b;
            b[0]=(f16)v0.x; b[1]=(f16)v0.y; b[2]=(f16)v0.z; b[3]=(f16)v0.w;
            b[4]=(f16)v1.x; b[5]=(f16)v1.y; b[6]=(f16)v1.z; b[7]=(f16)v1.w;
            acc[nt] = MFMA(a, b, acc[nt]);
        }
    }
    #pragma unroll
    for (int nt = 0; nt < 4; ++nt) {
        const int nn = n0 + nt*16 + l16;
        const float bi = bias[nn];
        #pragma unroll
        for (int r = 0; r < 4; ++r)
            out[(long)(m0 + quad*4 + r)*32000 + nn] = fmaxf(acc[nt][r] + bi, 0.f);
    }
}

// ---------------------------------------------------------- count -----------
__global__ void k_count(const float* __restrict__ scores, float* __restrict__ outc)
{
    const int row = blockIdx.x, tid = threadIdx.x;
    const float* p = scores + (long)row*32000;
    int cnt = 0;
    for (int i = tid; i < 32000; i += 256)
        cnt += ((double)p[i] > 0.6400000000000001) ? 1 : 0;
    __shared__ int red[256];
    red[tid] = cnt; __syncthreads();
    for (int off = 128; off > 0; off >>= 1) {
        if (tid < off) red[tid] += red[tid + off];
        __syncthreads();
    }
    if (tid == 0) outc[row] = (float)(red[0] < 1 ? 1 : red[0]);
}

// ---------------------------------------------------------- launch ----------
extern "C" void kernel_launch(void* const* d_in, const int* in_sizes, int n_in,
                              void* d_out, int out_size, void* d_ws, size_t ws_size,
                              hipStream_t stream)
{
    const float* x1    = (const float*)d_in[0];
    const float* x2    = (const float*)d_in[1];
    const float* Wih0  = (const float*)d_in[2];
    const float* Whh0  = (const float*)d_in[3];
    const float* bih0  = (const float*)d_in[4];
    const float* bhh0  = (const float*)d_in[5];
    const float* Wih1  = (const float*)d_in[6];
    const float* Whh1  = (const float*)d_in[7];
    const float* bih1  = (const float*)d_in[8];
    const float* bhh1  = (const float*)d_in[9];
    const float* fc1_w = (const float*)d_in[10];
    const float* fc1_b = (const float*)d_in[11];
    const float* fc2_w = (const float*)d_in[12];
    const float* fc2_b = (const float*)d_in[13];
    const float* fc3_w = (const float*)d_in[14];
    const float* fc3_b = (const float*)d_in[15];
    const float* bn_g  = (const float*)d_in[16];
    const float* bn_b  = (const float*)d_in[17];
    float* out = (float*)d_out;

    char* ws = (char*)d_ws;
    f16*   w16   = (f16*)(ws);                // 1,703,936 B
    float* bsum  = (float*)(ws + 1703936);    // 8,192 B
    int*   flags = (int*)(ws + 1712128);      // 2,048 B (16 flags x 128 B)
    float* enc   = (float*)(ws + 1714176);    // 131,072 B  [2][64][256]
    f16*   h0s   = (f16*)(ws + 1845248);      // 8,388,608 B  [128][128][256] step-major
    f16*   xg0   = (f16*)(ws + 10233856);     // 33,554,432 B [128 chains][128][1024]
    f16*   xg1   = (f16*)(ws + 43788288);     // 33,554,432 B (ends 77,342,720)
    float* h1    = (float*)(ws + 10233856);   // overlay xg0 region (dead after mega)
    f16*   h3f16 = (f16*)(ws + 10496000);     // [64][1024] f16 (131,072 B)

    k_convert<<<1024, 256, 0, stream>>>(Wih0,Whh0,bih0,bhh0,Wih1,Whh1,bih1,bhh1,
                                        w16, bsum, flags);
    // xg0 = x @ Wih0^T + (bih0+bhh0)  -> f16 gate-interleaved (fp32 cast inline)
    k_proj<64,true><<<dim3(128,8), 512, 0, stream>>>(x1, x2, w16, bsum, xg0);
    // pipelined layer0 | xg1-projection | layer1 (1024-thread blocks, 16 waves)
    k_mega<<<24, 1024, 0, stream>>>(w16, xg0, xg1, h0s, bsum + 1024, enc, flags);
    // head: fc1 (gelu, fp32) -> fc2 (+res, relu, fused BN -> f16) -> fc3 (MFMA)
    k_fc<512,0><<<32, 256, 0, stream>>>(enc, fc1_w, fc1_b, nullptr, nullptr, nullptr,
                                        h1, nullptr, 1024);
    k_fc<1024,1><<<32, 256, 0, stream>>>(h1, fc2_w, fc2_b, h1, bn_g, bn_b,
                                         nullptr, h3f16, 1024);
    k_fc3<<<500, 256, 0, stream>>>(h3f16, fc3_w, fc3_b, out);
    k_count<<<64, 256, 0, stream>>>(out, out + 2048000);
}

// Round 10
// 931.147 us; speedup vs baseline: 1.3937x; 1.3937x over previous
//
#include <hip/hip_runtime.h>
#include <cmath>

// ConceptLearner LSTM on MI355X.
// Sizes: B=64, S=128, D=64, H=256 (4H=1024 gates), P=1024, V*R=32000.
// R10: R7 config (512-thr mega, depth-2 chunks) + q-interleaved kc loop:
// a-fragment read ONCE per kc (was re-read per q; hb write blocked CSE),
// both q accumulator sets live. LDS reads/wave/step 32 -> 24 b128.
// R9 lesson: 1024-thr blocks halve the per-wave register budget -> bres
// spills; weights-in-registers caps us at 2 waves/SIMD. Do not revisit.

typedef _Float16 f16;
typedef _Float16 f16x8 __attribute__((ext_vector_type(8)));
typedef _Float16 f16x4 __attribute__((ext_vector_type(4)));
typedef float f32x4 __attribute__((ext_vector_type(4)));

#define MFMA(a,b,c) __builtin_amdgcn_mfma_f32_16x16x32_f16((a),(b),(c),0,0,0)
#define LSTR 280   // LDS row stride in f16
#define FPAD 32    // flag padding: 32 ints = 128 B per flag

__device__ __forceinline__ float frcp(float x) { return __builtin_amdgcn_rcpf(x); }
__device__ __forceinline__ float sigf(float x)  { return frcp(1.f + __expf(-x)); }
__device__ __forceinline__ float tanhf_(float x){ return 1.f - 2.f*frcp(__expf(2.f*x) + 1.f); }

// Relaxed spin until flag >= target, then one acquire load (inv) to fence data.
__device__ __forceinline__ void wait_flag(int* f, int target) {
    while (__hip_atomic_load(f, __ATOMIC_RELAXED, __HIP_MEMORY_SCOPE_AGENT) < target)
        __builtin_amdgcn_s_sleep(1);
    (void)__hip_atomic_load(f, __ATOMIC_ACQUIRE, __HIP_MEMORY_SCOPE_AGENT);
}

// ---------------------------------------------------------------- convert ---
__global__ void k_convert(const float* __restrict__ Wih0, const float* __restrict__ Whh0,
                          const float* __restrict__ bih0, const float* __restrict__ bhh0,
                          const float* __restrict__ Wih1, const float* __restrict__ Whh1,
                          const float* __restrict__ bih1, const float* __restrict__ bhh1,
                          f16* __restrict__ w16, float* __restrict__ bsum,
                          int* __restrict__ flg)
{
    int i = blockIdx.x * 256 + threadIdx.x;           // grid 1024*256
    if (i < 65536)  w16[i] = (f16)Wih0[i];            // Wih0 [1024][64]
    if (i < 262144) {
        w16[65536  + i] = (f16)Whh0[i];               // Whh0 [1024][256]
        w16[327680 + i] = (f16)Wih1[i];               // Wih1 [1024][256]
        w16[589824 + i] = (f16)Whh1[i];               // Whh1 [1024][256]
    }
    if (i < 1024) { bsum[i] = bih0[i] + bhh0[i]; bsum[1024 + i] = bih1[i] + bhh1[i]; }
    if (i < 16*FPAD) flg[i] = 0;                      // padded pipeline flags
}

// ------------------------------------------------- input projection (MFMA) --
// out preacts stored f16, gate-interleaved: row offset = ti*64 + col*4 + gate.
// CVT=true: A is fp32 (x1 rows 0..8191, x2 rows 8192..16383), cast inline.
template<int K, bool CVT>
__global__ __launch_bounds__(512)
void k_proj(const void* __restrict__ A0v, const void* __restrict__ A1v,
            const f16* __restrict__ Bw, const float* __restrict__ bias,
            f16* __restrict__ out)
{
    const int w = threadIdx.x >> 6, lane = threadIdx.x & 63;
    const int quad = lane >> 4, l16 = lane & 15;
    const long m0 = (long)blockIdx.x * 128 + w * 16;   // wave's M-tile
    f32x4 acc[2][4] = {};
    #pragma unroll
    for (int kc = 0; kc < K/32; ++kc) {
        const int ko = kc*32 + quad*8;
        f16x8 a;
        if (CVT) {
            const float* Af = (const float*)((m0 < 8192) ? A0v : A1v);
            const float* ap = Af + ((m0 & 8191) + l16)*K + ko;
            float4 v0 = *(const float4*)ap, v1 = *(const float4*)(ap + 4);
            a[0]=(f16)v0.x; a[1]=(f16)v0.y; a[2]=(f16)v0.z; a[3]=(f16)v0.w;
            a[4]=(f16)v1.x; a[5]=(f16)v1.y; a[6]=(f16)v1.z; a[7]=(f16)v1.w;
        } else {
            a = *(const f16x8*)((const f16*)A0v + (m0 + l16)*K + ko);
        }
        #pragma unroll
        for (int tg = 0; tg < 2; ++tg) {
            const int ti = blockIdx.y*2 + tg;
            #pragma unroll
            for (int g = 0; g < 4; ++g) {
                f16x8 b = *(const f16x8*)(Bw + (long)(g*256 + ti*16 + l16)*K + ko);
                acc[tg][g] = MFMA(a, b, acc[tg][g]);
            }
        }
    }
    #pragma unroll
    for (int tg = 0; tg < 2; ++tg) {
        const int ti = blockIdx.y*2 + tg;
        float bi[4];
        #pragma unroll
        for (int g = 0; g < 4; ++g) bi[g] = bias[g*256 + ti*16 + l16];
        #pragma unroll
        for (int r = 0; r < 4; ++r) {                  // D: row=quad*4+r, col=lane&15
            long mm = m0 + quad*4 + r;
            f16x4 pv;
            #pragma unroll
            for (int g = 0; g < 4; ++g) pv[g] = (f16)(acc[tg][g][r] + bi[g]);
            *(f16x4*)(out + mm*1024 + ti*64 + l16*4) = pv;
        }
    }
}

// --------------------------------------------- pipelined LSTM mega-kernel ---
// 24 blocks x 512 thr. role = blockIdx>>3: 0=layer0, 1=xg1 projection, 2=layer1.
// g = blockIdx&7 selects the 16-chain group. 2-step chunks:
// flags[g*FPAD]     : h0 progress  (v => h0(0..v-1) ready; released at even s)
// flags[(8+g)*FPAD] : xg1 progress (v => xg1(0..v-1) ready; released at odd s)
__global__ __launch_bounds__(512, 2)
void k_mega(const f16* __restrict__ w16, const f16* __restrict__ xg0,
            f16* __restrict__ xg1, f16* __restrict__ h0s,
            const float* __restrict__ bsum1, float* __restrict__ out_enc,
            int* __restrict__ flags)
{
    __shared__ f16 wl[256*LSTR];    // o-gate rows 768..1023 of this role's W
    __shared__ f16 hb[2*16*LSTR];   // double-buffered h (lstm roles only)
    const int tid = threadIdx.x;
    const int w = tid >> 6, lane = tid & 63;
    const int quad = lane >> 4, l16 = lane & 15;
    const int role = blockIdx.x >> 3, g = blockIdx.x & 7;
    int* fl_h0  = flags + g*FPAD;
    int* fl_xg1 = flags + (8+g)*FPAD;

    const f16* W = (role == 0) ? w16 + 65536           // Whh0
                 : (role == 1) ? w16 + 327680          // Wih1
                               : w16 + 589824;         // Whh1

    // resident b-frags: slots {i:0,1  f:2,3  g:4,5}; tile = (slot>>1)*16 + 2w + (slot&1)
    f16x8 bres[6][8];
    #pragma unroll
    for (int s6 = 0; s6 < 6; ++s6) {
        const int tile = (s6 >> 1)*16 + 2*w + (s6 & 1);
        #pragma unroll
        for (int kc = 0; kc < 8; ++kc)
            bres[s6][kc] = *(const f16x8*)(W + (tile*16 + l16)*256 + kc*32 + quad*8);
    }
    {   // stage o-gate rows into LDS (coalesced, once)
        const int r = tid >> 1, hh = tid & 1;
        const f16* src = W + (768 + r)*256 + hh*128;
        f16* dst = wl + r*LSTR + hh*128;
        #pragma unroll
        for (int j = 0; j < 16; ++j)
            *(f16x8*)(dst + j*8) = *(const f16x8*)(src + j*8);
    }

    if (role == 1) {    // ---------------- projection stage: xg1(s) = h0(s)@Wih1^T + b
        float bi[2][4];
        #pragma unroll
        for (int q = 0; q < 2; ++q)
            #pragma unroll
            for (int g4 = 0; g4 < 4; ++g4) bi[q][g4] = bsum1[g4*256 + (2*w+q)*16 + l16];
        __syncthreads();
        #pragma unroll 1
        for (int s = 0; s < 128; ++s) {
            if ((s & 1) == 0) {              // chunk head: wait for h0(s), h0(s+1)
                if (tid == 0) wait_flag(fl_h0, s + 2);
                __syncthreads();
            }
            const f16* hrow = h0s + ((long)s*128 + g*16 + l16)*256 + quad*8;
            f32x4 ai[2] = {}, af[2] = {}, ag[2] = {}, ao[2] = {};
            #pragma unroll
            for (int kc = 0; kc < 8; ++kc) {
                f16x8 a   = *(const f16x8*)(hrow + kc*32);
                f16x8 bo0 = *(const f16x8*)(wl + ((2*w  )*16 + l16)*LSTR + kc*32 + quad*8);
                f16x8 bo1 = *(const f16x8*)(wl + ((2*w+1)*16 + l16)*LSTR + kc*32 + quad*8);
                ai[0] = MFMA(a, bres[0][kc], ai[0]);
                af[0] = MFMA(a, bres[2][kc], af[0]);
                ag[0] = MFMA(a, bres[4][kc], ag[0]);
                ao[0] = MFMA(a, bo0,         ao[0]);
                ai[1] = MFMA(a, bres[1][kc], ai[1]);
                af[1] = MFMA(a, bres[3][kc], af[1]);
                ag[1] = MFMA(a, bres[5][kc], ag[1]);
                ao[1] = MFMA(a, bo1,         ao[1]);
            }
            #pragma unroll
            for (int q = 0; q < 2; ++q) {
                const int ti = 2*w + q;
                #pragma unroll
                for (int r = 0; r < 4; ++r) {
                    f16x4 pv;
                    pv[0] = (f16)(ai[q][r] + bi[q][0]);
                    pv[1] = (f16)(af[q][r] + bi[q][1]);
                    pv[2] = (f16)(ag[q][r] + bi[q][2]);
                    pv[3] = (f16)(ao[q][r] + bi[q][3]);
                    *(f16x4*)(xg1 + ((long)(g*16 + quad*4 + r)*128 + s)*1024
                                  + ti*64 + l16*4) = pv;
                }
            }
            if (s & 1) {                     // chunk tail: drain stores, release
                __syncthreads();             // vmcnt(0) before s_barrier
                if (tid == 0)
                    __hip_atomic_store(fl_xg1, s + 1, __ATOMIC_RELEASE,
                                       __HIP_MEMORY_SCOPE_AGENT);
            }
        }
        return;
    }

    // ---------------- LSTM stages (role 0 = layer0, role 2 = layer1) ----------
    for (int i = tid; i < 2*16*LSTR; i += 512) hb[i] = (f16)0.f;   // h(-1)=0

    const f16* xg = (role == 0) ? xg0 : xg1;
    const f16* xp[4];
    #pragma unroll
    for (int r = 0; r < 4; ++r)
        xp[r] = xg + (long)(g*16 + quad*4 + r)*131072 + (2*w)*64 + l16*4;

    float c[8]    = {0,0,0,0,0,0,0,0};
    float oacc[8] = {0,0,0,0,0,0,0,0};
    __syncthreads();

    #pragma unroll 1
    for (int s = 0; s < 128; ++s) {
        const int rb = s & 1, wb = rb ^ 1;
        if (role == 2 && (s & 1) == 0) {     // chunk head: wait for xg1(s), xg1(s+1)
            if (tid == 0) wait_flag(fl_xg1, s + 2);
            __syncthreads();
        }
        if (role == 0 && s > 0) {   // h(s-1) -> global (step-major), off critical path
            const int cc = tid >> 5, kk = (tid & 31) * 8;
            f16x8 hv = *(const f16x8*)(hb + (rb*16 + cc)*LSTR + kk);
            *(f16x8*)(h0s + ((long)(s-1)*128 + g*16 + cc)*256 + kk) = hv;
        }
        f16x4 xv[2][4];
        #pragma unroll
        for (int r = 0; r < 4; ++r) {
            xv[0][r] = *(const f16x4*)(xp[r]);
            xv[1][r] = *(const f16x4*)(xp[r] + 64);
        }
        // q-interleaved kc loop: a read ONCE, both q acc sets live
        f32x4 ai[2] = {}, af[2] = {}, ag[2] = {}, ao[2] = {};
        #pragma unroll
        for (int kc = 0; kc < 8; ++kc) {
            f16x8 a   = *(const f16x8*)(hb + (rb*16 + l16)*LSTR + kc*32 + quad*8);
            f16x8 bo0 = *(const f16x8*)(wl + ((2*w  )*16 + l16)*LSTR + kc*32 + quad*8);
            f16x8 bo1 = *(const f16x8*)(wl + ((2*w+1)*16 + l16)*LSTR + kc*32 + quad*8);
            ai[0] = MFMA(a, bres[0][kc], ai[0]);
            af[0] = MFMA(a, bres[2][kc], af[0]);
            ag[0] = MFMA(a, bres[4][kc], ag[0]);
            ao[0] = MFMA(a, bo0,         ao[0]);
            ai[1] = MFMA(a, bres[1][kc], ai[1]);
            af[1] = MFMA(a, bres[3][kc], af[1]);
            ag[1] = MFMA(a, bres[5][kc], ag[1]);
            ao[1] = MFMA(a, bo1,         ao[1]);
        }
        #pragma unroll
        for (int q = 0; q < 2; ++q) {
            const int ti = 2*w + q;
            #pragma unroll
            for (int r = 0; r < 4; ++r) {
                float gi = sigf(ai[q][r] + (float)xv[q][r][0]);
                float gf = sigf(af[q][r] + (float)xv[q][r][1]);
                float gg = tanhf_(ag[q][r] + (float)xv[q][r][2]);
                float go = sigf(ao[q][r] + (float)xv[q][r][3]);
                const int ci = q*4 + r;
                float cn = gf*c[ci] + gi*gg;
                c[ci] = cn;
                float hn = go * tanhf_(cn);
                if (role == 2) oacc[ci] += hn;
                hb[(wb*16 + quad*4 + r)*LSTR + ti*16 + l16] = (f16)hn;
            }
        }
        #pragma unroll
        for (int r = 0; r < 4; ++r) xp[r] += 1024;
        __syncthreads();           // drains the h(s-1) global store (vmcnt)
        // release at even steps s>=2: h0(0..s-1) globally visible
        if (role == 0 && (s & 1) == 0 && s > 0 && tid == 0)
            __hip_atomic_store(fl_h0, s, __ATOMIC_RELEASE,
                               __HIP_MEMORY_SCOPE_AGENT);
    }
    if (role == 0) {       // final history entry h(127): buffer rb(128)=0
        const int cc = tid >> 5, kk = (tid & 31) * 8;
        f16x8 hv = *(const f16x8*)(hb + (0*16 + cc)*LSTR + kk);
        *(f16x8*)(h0s + ((long)127*128 + g*16 + cc)*256 + kk) = hv;
        __syncthreads();
        if (tid == 0)
            __hip_atomic_store(fl_h0, 128, __ATOMIC_RELEASE,
                               __HIP_MEMORY_SCOPE_AGENT);
    }
    if (role == 2) {       // time-summed hidden state -> encoder output
        #pragma unroll
        for (int q = 0; q < 2; ++q)
            #pragma unroll
            for (int r = 0; r < 4; ++r)
                out_enc[(long)(g*16 + quad*4 + r)*256 + (2*w+q)*16 + l16] = oacc[q*4 + r];
    }
}

// ----------------------------------------------------- fp32 FC (head) -------
// MODE 0: gelu (A = concat(enc0,enc1)) -> fp32 out; MODE 1: res+relu then
// fused BatchNorm (block owns all 64 rows of its 32 cols) -> f16 out16.
template<int K, int MODE>
__global__ __launch_bounds__(256)
void k_fc(const float* __restrict__ A, const float* __restrict__ W,
          const float* __restrict__ bias, const float* __restrict__ res,
          const float* __restrict__ bng, const float* __restrict__ bnb,
          float* __restrict__ out, f16* __restrict__ out16, const int Nst)
{
    __shared__ float ws[32*64];
    __shared__ float as[64*64];   // [k][m]; MODE 1 reuses as stride-33 stats buffer
    __shared__ float mus[32], rss[32];
    const int tid = threadIdx.x;
    const int n0 = blockIdx.x * 32;
    const int m2 = tid & 31, ndg = tid >> 5;
    float acc[2][4] = {};
    for (int kc = 0; kc < K/64; ++kc) {
        __syncthreads();
        {   // stage W [32 cols][64 k]
            const int col = tid >> 3, k8 = (tid & 7)*8;
            const float* src = W + (long)(n0 + col)*K + kc*64 + k8;
            *(float4*)(ws + col*64 + k8)     = *(const float4*)(src);
            *(float4*)(ws + col*64 + k8 + 4) = *(const float4*)(src + 4);
        }
        {   // stage A transposed: as[k][m]
            const int m = tid >> 2, j4 = (tid & 3)*16;
            #pragma unroll
            for (int i4 = 0; i4 < 4; ++i4) {
                const int kk = kc*64 + j4 + i4*4;
                const float* srcA;
                if (MODE == 0) srcA = (kk < 256) ? (A + (long)m*256 + kk)
                                                 : (A + 16384 + (long)m*256 + kk - 256);
                else           srcA = A + (long)m*K + kk;
                float4 v = *(const float4*)srcA;
                as[(j4 + i4*4 + 0)*64 + m] = v.x;
                as[(j4 + i4*4 + 1)*64 + m] = v.y;
                as[(j4 + i4*4 + 2)*64 + m] = v.z;
                as[(j4 + i4*4 + 3)*64 + m] = v.w;
            }
        }
        __syncthreads();
        #pragma unroll 4
        for (int k4 = 0; k4 < 64; k4 += 4) {
            float a0[4], a1[4];
            #pragma unroll
            for (int i = 0; i < 4; ++i) {
                a0[i] = as[(k4+i)*64 + m2];
                a1[i] = as[(k4+i)*64 + m2 + 32];
            }
            #pragma unroll
            for (int j = 0; j < 4; ++j) {
                const float4 wv = *(const float4*)(ws + (ndg*4 + j)*64 + k4);
                acc[0][j] += a0[0]*wv.x + a0[1]*wv.y + a0[2]*wv.z + a0[3]*wv.w;
                acc[1][j] += a1[0]*wv.x + a1[1]*wv.y + a1[2]*wv.z + a1[3]*wv.w;
            }
        }
    }
    if (MODE == 1) {                       // res + relu, then fused BatchNorm
        float vv[2][4];
        #pragma unroll
        for (int i = 0; i < 2; ++i)
            #pragma unroll
            for (int j = 0; j < 4; ++j) {
                const int m = m2 + i*32, nn = n0 + ndg*4 + j;
                vv[i][j] = res[(long)m*1024 + nn] + fmaxf(acc[i][j] + bias[nn], 0.f);
            }
        __syncthreads();                    // as[] compute reads done
        #pragma unroll
        for (int i = 0; i < 2; ++i)
            #pragma unroll
            for (int j = 0; j < 4; ++j)
                as[(m2 + i*32)*33 + ndg*4 + j] = vv[i][j];   // stride 33: skewed banks
        __syncthreads();
        if (tid < 32) {
            float s = 0.f, ss = 0.f;
            #pragma unroll 4
            for (int m = 0; m < 64; ++m) {
                float x = as[m*33 + tid];
                s += x; ss += x*x;
            }
            const float mu = s * (1.f/64.f);
            mus[tid] = mu;
            rss[tid] = rsqrtf(ss * (1.f/64.f) - mu*mu + 1e-5f);
        }
        __syncthreads();
        #pragma unroll
        for (int i = 0; i < 2; ++i)
            #pragma unroll
            for (int j = 0; j < 4; ++j) {
                const int m = m2 + i*32, cl = ndg*4 + j, nn = n0 + cl;
                out16[(long)m*Nst + nn] =
                    (f16)((vv[i][j] - mus[cl]) * rss[cl] * bng[nn] + bnb[nn]);
            }
        return;
    }
    #pragma unroll
    for (int i = 0; i < 2; ++i) {
        const int m = m2 + i*32;
        #pragma unroll
        for (int j = 0; j < 4; ++j) {
            const int nn = n0 + ndg*4 + j;
            float v = acc[i][j] + bias[nn];
            v = 0.5f * v * (1.0f + erff(v * 0.7071067811865475f));
            out[(long)m*Nst + nn] = v;
        }
    }
}

// ------------------------------------- fc3: MFMA, W converted inline --------
// scores[m][n] = relu(h3f16[m][:] . fc3_w[n][:] + b[n]); M=64, N=32000, K=1024.
// W streamed from HBM as fp32 (used once), cast to f16 in-register; A f16 L2-hot.
__global__ __launch_bounds__(256)
void k_fc3(const f16* __restrict__ A, const float* __restrict__ W,
           const float* __restrict__ bias, float* __restrict__ out)
{
    const int w = threadIdx.x >> 6, lane = threadIdx.x & 63;
    const int quad = lane >> 4, l16 = lane & 15;
    const int m0 = w*16, n0 = blockIdx.x*64;
    f32x4 acc[4] = {};
    #pragma unroll 1
    for (int kc = 0; kc < 32; ++kc) {
        const int ko = kc*32 + quad*8;
        f16x8 a = *(const f16x8*)(A + (m0 + l16)*1024 + ko);
        #pragma unroll
        for (int nt = 0; nt < 4; ++nt) {
            const float* wp = W + (long)(n0 + nt*16 + l16)*1024 + ko;
            float4 v0 = *(const float4*)wp, v1 = *(const float4*)(wp + 4);
            f16x8 b;
            b[0]=(f16)v0.x; b[1]=(f16)v0.y; b[2]=(f16)v0.z; b[3]=(f16)v0.w;
            b[4]=(f16)v1.x; b[5]=(f16)v1.y; b[6]=(f16)v1.z; b[7]=(f16)v1.w;
            acc[nt] = MFMA(a, b, acc[nt]);
        }
    }
    #pragma unroll
    for (int nt = 0; nt < 4; ++nt) {
        const int nn = n0 + nt*16 + l16;
        const float bi = bias[nn];
        #pragma unroll
        for (int r = 0; r < 4; ++r)
            out[(long)(m0 + quad*4 + r)*32000 + nn] = fmaxf(acc[nt][r] + bi, 0.f);
    }
}

// ---------------------------------------------------------- count -----------
__global__ void k_count(const float* __restrict__ scores, float* __restrict__ outc)
{
    const int row = blockIdx.x, tid = threadIdx.x;
    const float* p = scores + (long)row*32000;
    int cnt = 0;
    for (int i = tid; i < 32000; i += 256)
        cnt += ((double)p[i] > 0.6400000000000001) ? 1 : 0;
    __shared__ int red[256];
    red[tid] = cnt; __syncthreads();
    for (int off = 128; off > 0; off >>= 1) {
        if (tid < off) red[tid] += red[tid + off];
        __syncthreads();
    }
    if (tid == 0) outc[row] = (float)(red[0] < 1 ? 1 : red[0]);
}

// ---------------------------------------------------------- launch ----------
extern "C" void kernel_launch(void* const* d_in, const int* in_sizes, int n_in,
                              void* d_out, int out_size, void* d_ws, size_t ws_size,
                              hipStream_t stream)
{
    const float* x1    = (const float*)d_in[0];
    const float* x2    = (const float*)d_in[1];
    const float* Wih0  = (const float*)d_in[2];
    const float* Whh0  = (const float*)d_in[3];
    const float* bih0  = (const float*)d_in[4];
    const float* bhh0  = (const float*)d_in[5];
    const float* Wih1  = (const float*)d_in[6];
    const float* Whh1  = (const float*)d_in[7];
    const float* bih1  = (const float*)d_in[8];
    const float* bhh1  = (const float*)d_in[9];
    const float* fc1_w = (const float*)d_in[10];
    const float* fc1_b = (const float*)d_in[11];
    const float* fc2_w = (const float*)d_in[12];
    const float* fc2_b = (const float*)d_in[13];
    const float* fc3_w = (const float*)d_in[14];
    const float* fc3_b = (const float*)d_in[15];
    const float* bn_g  = (const float*)d_in[16];
    const float* bn_b  = (const float*)d_in[17];
    float* out = (float*)d_out;

    char* ws = (char*)d_ws;
    f16*   w16   = (f16*)(ws);                // 1,703,936 B
    float* bsum  = (float*)(ws + 1703936);    // 8,192 B
    int*   flags = (int*)(ws + 1712128);      // 2,048 B (16 flags x 128 B)
    float* enc   = (float*)(ws + 1714176);    // 131,072 B  [2][64][256]
    f16*   h0s   = (f16*)(ws + 1845248);      // 8,388,608 B  [128][128][256] step-major
    f16*   xg0   = (f16*)(ws + 10233856);     // 33,554,432 B [128 chains][128][1024]
    f16*   xg1   = (f16*)(ws + 43788288);     // 33,554,432 B (ends 77,342,720)
    float* h1    = (float*)(ws + 10233856);   // overlay xg0 region (dead after mega)
    f16*   h3f16 = (f16*)(ws + 10496000);     // [64][1024] f16 (131,072 B)

    k_convert<<<1024, 256, 0, stream>>>(Wih0,Whh0,bih0,bhh0,Wih1,Whh1,bih1,bhh1,
                                        w16, bsum, flags);
    // xg0 = x @ Wih0^T + (bih0+bhh0)  -> f16 gate-interleaved (fp32 cast inline)
    k_proj<64,true><<<dim3(128,8), 512, 0, stream>>>(x1, x2, w16, bsum, xg0);
    // pipelined layer0 | xg1-projection | layer1
    k_mega<<<24, 512, 0, stream>>>(w16, xg0, xg1, h0s, bsum + 1024, enc, flags);
    // head: fc1 (gelu, fp32) -> fc2 (+res, relu, fused BN -> f16) -> fc3 (MFMA)
    k_fc<512,0><<<32, 256, 0, stream>>>(enc, fc1_w, fc1_b, nullptr, nullptr, nullptr,
                                        h1, nullptr, 1024);
    k_fc<1024,1><<<32, 256, 0, stream>>>(h1, fc2_w, fc2_b, h1, bn_g, bn_b,
                                         nullptr, h3f16, 1024);
    k_fc3<<<500, 256, 0, stream>>>(h3f16, fc3_w, fc3_b, out);
    k_count<<<64, 256, 0, stream>>>(out, out + 2048000);
}